// Round 3
// baseline (3635.201 us; speedup 1.0000x reference)
//
#include <hip/hip_runtime.h>
#include <math.h>

typedef __bf16 bf16;
typedef __bf16 bf16x8 __attribute__((ext_vector_type(8)));
typedef float f32x4 __attribute__((ext_vector_type(4)));

// Problem dims
#define NQ   32
#define NN_  128
#define TT   352
#define DD   768
#define NH   8
#define HDIM 96
#define LSEQ 512
#define TSPLIT 160          // NQ + NN
#define FFD  3072
#define NLAYER 6
#define NBATCH 16

// ---------------------------------------------------------------------------
// bt-GEMM (bf16 internal): C[M,N] = act(alpha * A[M,K] @ Bt[N,K]^T + bias[N])
// 128x128 tile, BK=32, 256 threads (4 waves, 2x2 of 64x64), mfma 16x16x32.
// A, Bt, C are bf16 workspace buffers; bias is fp32 (harness input).
// Batched via grid.z: z1 = z/zdiv, z2 = z%zdiv.
// ---------------------------------------------------------------------------
template <int ACT>
__global__ __launch_bounds__(256) void gemm_bt(
    const bf16* __restrict__ A, const bf16* __restrict__ Bt,
    bf16* __restrict__ C, const float* __restrict__ bias,
    int K, int lda, int ldb, int ldc, int zdiv,
    long sA1, long sA2, long sB1, long sB2, long sC1, long sC2,
    float alpha, int Nstore)
{
    __shared__ __attribute__((aligned(16))) bf16 As[128 * 32];
    __shared__ __attribute__((aligned(16))) bf16 Bs[128 * 32];

    const int bz = blockIdx.z;
    const int z1 = bz / zdiv, z2 = bz % zdiv;
    A  += (size_t)z1 * sA1 + (size_t)z2 * sA2;
    Bt += (size_t)z1 * sB1 + (size_t)z2 * sB2;
    C  += (size_t)z1 * sC1 + (size_t)z2 * sC2;

    const int n0 = blockIdx.x * 128, m0 = blockIdx.y * 128;
    const int t = threadIdx.x;
    const int w = t >> 6, l = t & 63;
    const int wm = w >> 1, wn = w & 1;
    const int lr = l & 15, quad = l >> 4;

    f32x4 acc[4][4] = {};

    // staging map: thread t covers flat tile elems [t*8, t*8+8) and
    // [2048 + t*8, ...). flat f -> row f>>5, col f&31 (tile is [128][32]).
    const int f0 = t * 8;
    const int sr0 = f0 >> 5, sc0 = f0 & 31;   // rows 0..63
    const int sr1 = sr0 + 64;                 // rows 64..127

    for (int k0 = 0; k0 < K; k0 += 32) {
        bf16x8 va0 = *(const bf16x8*)&A [(size_t)(m0 + sr0) * lda + k0 + sc0];
        bf16x8 va1 = *(const bf16x8*)&A [(size_t)(m0 + sr1) * lda + k0 + sc0];
        bf16x8 vb0 = *(const bf16x8*)&Bt[(size_t)(n0 + sr0) * ldb + k0 + sc0];
        bf16x8 vb1 = *(const bf16x8*)&Bt[(size_t)(n0 + sr1) * ldb + k0 + sc0];
        __syncthreads();                       // prev iter's LDS reads done
        *(bf16x8*)&As[f0]        = va0;
        *(bf16x8*)&As[f0 + 2048] = va1;
        *(bf16x8*)&Bs[f0]        = vb0;
        *(bf16x8*)&Bs[f0 + 2048] = vb1;
        __syncthreads();                       // staged data visible

        bf16x8 af[4], bf_[4];
#pragma unroll
        for (int i = 0; i < 4; ++i)
            af[i] = *(const bf16x8*)&As[(wm * 64 + i * 16 + lr) * 32 + quad * 8];
#pragma unroll
        for (int j = 0; j < 4; ++j)
            bf_[j] = *(const bf16x8*)&Bs[(wn * 64 + j * 16 + lr) * 32 + quad * 8];
#pragma unroll
        for (int i = 0; i < 4; ++i)
#pragma unroll
            for (int j = 0; j < 4; ++j)
                acc[i][j] = __builtin_amdgcn_mfma_f32_16x16x32_bf16(af[i], bf_[j], acc[i][j], 0, 0, 0);
    }

    // epilogue: C/D layout col = lane&15, row = quad*4 + reg (m89/m91-verified)
#pragma unroll
    for (int i = 0; i < 4; ++i) {
        const int grow = m0 + wm * 64 + i * 16 + quad * 4;
#pragma unroll
        for (int j = 0; j < 4; ++j) {
            const int gcol = n0 + wn * 64 + j * 16 + lr;
            if (gcol >= Nstore) continue;
            float bv = bias ? bias[gcol] : 0.0f;
#pragma unroll
            for (int r = 0; r < 4; ++r) {
                float v = acc[i][j][r] * alpha + bv;
                if (ACT == 1) v = 0.5f * v * (1.0f + erff(v * 0.70710678118654752f));
                C[(size_t)(grow + r) * ldc + gcol] = (bf16)v;
            }
        }
    }
}

// ---------------------------------------------------------------------------
// transpose fp32 weight [R][C] -> bf16 [C][R]
// ---------------------------------------------------------------------------
__global__ void transpose_w(const float* __restrict__ in, bf16* __restrict__ out,
                            int R, int C)
{
    __shared__ bf16 tile[32][33];
    const float* src = in;
    bf16* dst = out;
    const int c0 = blockIdx.x * 32, r0 = blockIdx.y * 32;
    const int tx = threadIdx.x & 31, ty = threadIdx.x >> 5;
    for (int i = ty; i < 32; i += 8)
        tile[i][tx] = (bf16)src[(size_t)(r0 + i) * C + c0 + tx];
    __syncthreads();
    for (int i = ty; i < 32; i += 8)
        dst[(size_t)(c0 + i) * R + r0 + tx] = tile[tx][i];
}

// fp32 -> bf16 elementwise
__global__ void cvt_bf16(const float* __restrict__ in, bf16* __restrict__ out, int n)
{
    const int idx = blockIdx.x * 256 + threadIdx.x;
    if (idx < n) out[idx] = (bf16)in[idx];
}

// vT[z][d][l] = qkv[zb][l][1536 + h*96 + d], z = zb*8+h (zb = chunk-local
// batch, 4 per chunk). Rows d=96..127 zero-filled (pad for 128-wide staging).
__global__ void transpose_v(const bf16* __restrict__ qkv, bf16* __restrict__ vT)
{
    __shared__ bf16 tile[32][33];
    const int z = blockIdx.z;
    const int zb = z >> 3, h = z & 7;
    const bf16* src = qkv + (size_t)zb * LSEQ * 2304 + 1536 + h * HDIM;
    bf16* dst = vT + (size_t)z * 128 * LSEQ;
    const int l0 = blockIdx.x * 32, d0 = blockIdx.y * 32;
    const int tx = threadIdx.x & 31, ty = threadIdx.x >> 5;
    for (int i = ty; i < 32; i += 8)
        tile[i][tx] = (d0 + tx < HDIM) ? src[(size_t)(l0 + i) * 2304 + d0 + tx]
                                       : (bf16)0.f;
    __syncthreads();
    for (int i = ty; i < 32; i += 8)
        dst[(size_t)(d0 + i) * LSEQ + l0 + tx] = tile[tx][i];
}

// ---------------------------------------------------------------------------
// reductions / LN
// ---------------------------------------------------------------------------
__device__ __forceinline__ void block_reduce_2(float& a, float& b)
{
#pragma unroll
    for (int off = 32; off; off >>= 1) {
        a += __shfl_xor(a, off);
        b += __shfl_xor(b, off);
    }
    __shared__ float sa[4], sb[4];
    const int w = threadIdx.x >> 6;
    if ((threadIdx.x & 63) == 0) { sa[w] = a; sb[w] = b; }
    __syncthreads();
    a = sa[0] + sa[1] + sa[2] + sa[3];
    b = sb[0] + sb[1] + sb[2] + sb[3];
}

// x[row] = LN(concat_src(row) + pos[l] + tok); fp32 inputs, bf16 out
__global__ void embed_ln(const float* __restrict__ qtok, const bf16* __restrict__ gfeat,
                         const float* __restrict__ text, const float* __restrict__ pos,
                         const float* __restrict__ tok, const float* __restrict__ g,
                         const float* __restrict__ bb, bf16* __restrict__ x)
{
    const int row = blockIdx.x;           // b*512 + l
    const int l = row & 511, b = row >> 9;
    const int t = threadIdx.x;

    float vals[3], s = 0.f, sq = 0.f;
#pragma unroll
    for (int c = 0; c < 3; ++c) {
        const int d = t + c * 256;
        float base;
        if (l < NQ)           base = qtok[(size_t)l * DD + d];
        else if (l < TSPLIT)  base = (float)gfeat[((size_t)b * NN_ + (l - NQ)) * DD + d];
        else                  base = text[((size_t)b * TT + (l - TSPLIT)) * DD + d];
        float v = base + pos[(size_t)l * DD + d] + tok[d];
        vals[c] = v; s += v; sq += v * v;
    }
    block_reduce_2(s, sq);
    const float mean = s * (1.f / 768.f);
    const float var = sq * (1.f / 768.f) - mean * mean;
    const float rs = rsqrtf(var + 1e-12f);
    bf16* o = x + (size_t)row * DD;
#pragma unroll
    for (int c = 0; c < 3; ++c) {
        const int d = t + c * 256;
        o[d] = (bf16)((vals[c] - mean) * rs * g[d] + bb[d]);
    }
}

// out[row] = LN(X[row] + Y[row]); safe for out==X; fp32 gains
__global__ void ln_rows(const bf16* __restrict__ X, const bf16* __restrict__ Y,
                        bf16* __restrict__ Out, const float* __restrict__ g,
                        const float* __restrict__ bb)
{
    const int row = blockIdx.x;
    const int t = threadIdx.x;
    const bf16* xr = X + (size_t)row * DD;
    const bf16* yr = Y + (size_t)row * DD;
    float vals[3], s = 0.f, sq = 0.f;
#pragma unroll
    for (int c = 0; c < 3; ++c) {
        const int d = t + c * 256;
        float v = (float)xr[d] + (float)yr[d];
        vals[c] = v; s += v; sq += v * v;
    }
    block_reduce_2(s, sq);
    const float mean = s * (1.f / 768.f);
    const float var = sq * (1.f / 768.f) - mean * mean;
    const float rs = rsqrtf(var + 1e-12f);
    bf16* o = Out + (size_t)row * DD;
#pragma unroll
    for (int c = 0; c < 3; ++c) {
        const int d = t + c * 256;
        o[d] = (bf16)((vals[c] - mean) * rs * g[d] + bb[d]);
    }
}

// ---------------------------------------------------------------------------
// softmax with ITG prefix-LM mask bias, in place on S (bf16), 1 wave per row
// S layout: [z = zb*8+h][512 rows][512 cols]; global batch = b0 + zb
// ---------------------------------------------------------------------------
__global__ void softmax_mask(bf16* __restrict__ S, const int* __restrict__ tatts,
                             const int* __restrict__ gmask, int b0)
{
    const int wid = blockIdx.x * 4 + (threadIdx.x >> 6);
    const int lane = threadIdx.x & 63;
    const int i = wid & 511;
    const int bh = wid >> 9;
    const int b = b0 + (bh >> 3);
    bf16* p = S + (size_t)wid * 512;

    const int keep_i = (i < NQ) ? 1 : (i < TSPLIT ? gmask[b * NN_ + i - NQ]
                                                  : tatts[b * TT + i - TSPLIT]);
    float v[8];
    float m = -INFINITY;
#pragma unroll
    for (int c = 0; c < 8; ++c) {
        const int j = c * 64 + lane;
        const int keep_j = (j < NQ) ? 1 : (j < TSPLIT ? gmask[b * NN_ + j - NQ]
                                                      : tatts[b * TT + j - TSPLIT]);
        bool ok = keep_i && keep_j;
        if (i < TSPLIT && j >= TSPLIT) ok = false;             // prefix can't see text
        if (i >= TSPLIT && j >= TSPLIT && i < j) ok = false;   // causal in text block
        float s = (float)p[j] + (ok ? 0.f : -1e9f);
        v[c] = s;
        m = fmaxf(m, s);
    }
#pragma unroll
    for (int off = 32; off; off >>= 1) m = fmaxf(m, __shfl_xor(m, off));
    float sum = 0.f;
#pragma unroll
    for (int c = 0; c < 8; ++c) { v[c] = __expf(v[c] - m); sum += v[c]; }
#pragma unroll
    for (int off = 32; off; off >>= 1) sum += __shfl_xor(sum, off);
    const float inv = 1.f / sum;
#pragma unroll
    for (int c = 0; c < 8; ++c) p[c * 64 + lane] = (bf16)(v[c] * inv);
}

// d_out[b][t][d] = x[b][TSPLIT+t][d]  (fp32 out)
__global__ void copy_out(const bf16* __restrict__ x, float* __restrict__ out)
{
    const size_t idx = (size_t)blockIdx.x * 256 + threadIdx.x;   // < 16*352*768
    const int d = idx % DD;
    const size_t row = idx / DD;
    const int t = row % TT;
    const int b = row / TT;
    out[idx] = (float)x[((size_t)b * LSEQ + TSPLIT + t) * DD + d];
}

// ---------------------------------------------------------------------------
// host side
// ---------------------------------------------------------------------------
static void launch_gemm(const bf16* A, const bf16* Bt, bf16* C, const float* bias,
                        int M, int K, int lda, int ldb, int ldc,
                        int batches, int zdiv,
                        long sA1, long sA2, long sB1, long sB2, long sC1, long sC2,
                        float alpha, int Nstore, int act, hipStream_t stream)
{
    dim3 grid((Nstore + 127) / 128, M / 128, batches);
    if (act)
        gemm_bt<1><<<grid, 256, 0, stream>>>(A, Bt, C, bias, K, lda, ldb, ldc, zdiv,
                                             sA1, sA2, sB1, sB2, sC1, sC2, alpha, Nstore);
    else
        gemm_bt<0><<<grid, 256, 0, stream>>>(A, Bt, C, bias, K, lda, ldb, ldc, zdiv,
                                             sA1, sA2, sB1, sB2, sC1, sC2, alpha, Nstore);
}

extern "C" void kernel_launch(void* const* d_in, const int* in_sizes, int n_in,
                              void* d_out, int out_size, void* d_ws, size_t ws_size,
                              hipStream_t stream)
{
    // Reference dtypes: all float32 except text_atts / graph_mask (int32).
    const float* gnf     = (const float*)d_in[0];
    const float* text    = (const float*)d_in[1];
    const int*   tatts   = (const int*)d_in[2];
    const int*   gmask   = (const int*)d_in[3];
    const float* qtok    = (const float*)d_in[4];
    const float* gproj_w = (const float*)d_in[5];
    const float* gproj_b = (const float*)d_in[6];
    const float* pos     = (const float*)d_in[7];
    const float* tok     = (const float*)d_in[8];
    const float* eg      = (const float*)d_in[9];
    const float* eb      = (const float*)d_in[10];
    const float* qkv_w   = (const float*)d_in[11];
    const float* qkv_b   = (const float*)d_in[12];
    const float* ao_w    = (const float*)d_in[13];
    const float* ao_b    = (const float*)d_in[14];
    const float* ln1g    = (const float*)d_in[15];
    const float* ln1b    = (const float*)d_in[16];
    const float* ff1_w   = (const float*)d_in[17];
    const float* ff1_b   = (const float*)d_in[18];
    const float* ff2_w   = (const float*)d_in[19];
    const float* ff2_b   = (const float*)d_in[20];
    const float* ln2g    = (const float*)d_in[21];
    const float* ln2b    = (const float*)d_in[22];
    float* out = (float*)d_out;

    // ws layout (bf16 elements), total 40,894,464 elems = 81.8 MB.
    // Regions aliased only across disjoint live ranges.
    bf16* ws    = (bf16*)d_ws;
    bf16* wt1   = ws;                    // 2,359,296: current B^T (qkv/ao/ff1)
    bf16* wt2   = wt1 + 2359296;         // 2,359,296: ff2^T (live with ff1^T)
    bf16* x     = wt2 + 2359296;         // 6,291,456: residual stream
    bf16* qkvb  = x   + 6291456;         // 4,718,592: qkv for one 4-batch chunk
    bf16* ctx   = qkvb + 4718592;        // 6,291,456: attention context (full)
    bf16* t1    = ctx + 6291456;         // 6,291,456: sublayer output / gfeat
    bf16* u     = t1  + 6291456;         // 12,582,912: union region
    bf16* vTc   = u;                     //   2,097,152 (attn phase)
    bf16* Sc    = u + 2097152;           //   8,388,608 (attn phase)
    bf16* hbuf  = u;                     //   12,582,912 (ffn phase)
    bf16* gfeat = t1;                    //   1,572,864 (pre-loop only)
    bf16* gnfb  = qkvb;                  //   1,572,864 (pre-loop only)

    dim3 blk(256);

    // graph projection: gfeat[2048,768] = bf16(gnf) @ bf16(gproj_w) + b
    cvt_bf16<<<6144, blk, 0, stream>>>(gnf, gnfb, 1572864);
    transpose_w<<<dim3(24, 24), blk, 0, stream>>>(gproj_w, wt1, 768, 768);
    launch_gemm(gnfb, wt1, gfeat, gproj_b, 2048, 768, 768, 768, 768,
                1, 1, 0, 0, 0, 0, 0, 0, 1.f, 768, 0, stream);
    embed_ln<<<8192, blk, 0, stream>>>(qtok, gfeat, text, pos, tok, eg, eb, x);

    const float scale = 0.10206207261596577f;  // 1/sqrt(96)
    for (int i = 0; i < NLAYER; ++i) {
        // attention, chunked over 4 batches (32 (b,h) pairs) at a time
        transpose_w<<<dim3(72, 24), blk, 0, stream>>>(
            qkv_w + (size_t)i * 768 * 2304, wt1, 768, 2304);
        for (int c = 0; c < 4; ++c) {
            launch_gemm(x + (size_t)c * 2048 * 768, wt1, qkvb, qkv_b + i * 2304,
                        2048, 768, 768, 768, 2304, 1, 1, 0, 0, 0, 0, 0, 0,
                        1.f, 2304, 0, stream);
            transpose_v<<<dim3(16, 4, 32), blk, 0, stream>>>(qkvb, vTc);
            launch_gemm(qkvb, qkvb + 768, Sc, nullptr, 512, 96, 2304, 2304, 512,
                        32, 8, 1179648, 96, 1179648, 96, 2097152, 262144,
                        scale, 512, 0, stream);
            softmax_mask<<<4096, blk, 0, stream>>>(Sc, tatts, gmask, c * 4);
            launch_gemm(Sc, vTc, ctx + (size_t)c * 2048 * 768, nullptr,
                        512, 512, 512, 512, 768,
                        32, 8, 2097152, 262144, 524288, 65536, 393216, 96,
                        1.f, 96, 0, stream);
        }
        transpose_w<<<dim3(24, 24), blk, 0, stream>>>(
            ao_w + (size_t)i * 589824, wt1, 768, 768);
        launch_gemm(ctx, wt1, t1, ao_b + i * 768, 8192, 768, 768, 768, 768,
                    1, 1, 0, 0, 0, 0, 0, 0, 1.f, 768, 0, stream);
        ln_rows<<<8192, blk, 0, stream>>>(x, t1, x, ln1g + i * 768, ln1b + i * 768);

        // ffn, chunked x2 so hidden fits the union region
        transpose_w<<<dim3(96, 24), blk, 0, stream>>>(
            ff1_w + (size_t)i * 2359296, wt1, 768, 3072);
        transpose_w<<<dim3(24, 96), blk, 0, stream>>>(
            ff2_w + (size_t)i * 2359296, wt2, 3072, 768);
        for (int c = 0; c < 2; ++c) {
            launch_gemm(x + (size_t)c * 4096 * 768, wt1, hbuf, ff1_b + i * 3072,
                        4096, 768, 768, 768, 3072, 1, 1, 0, 0, 0, 0, 0, 0,
                        1.f, 3072, 1, stream);
            launch_gemm(hbuf, wt2, t1 + (size_t)c * 4096 * 768, ff2_b + i * 768,
                        4096, 3072, 3072, 3072, 768, 1, 1, 0, 0, 0, 0, 0, 0,
                        1.f, 768, 0, stream);
        }
        ln_rows<<<8192, blk, 0, stream>>>(x, t1, x, ln2g + i * 768, ln2b + i * 768);
    }

    copy_out<<<16896, blk, 0, stream>>>(x, out);

    (void)in_sizes; (void)n_in; (void)out_size; (void)ws_size;
}

// Round 4
// 2446.606 us; speedup vs baseline: 1.4858x; 1.4858x over previous
//
#include <hip/hip_runtime.h>
#include <math.h>

typedef __bf16 bf16;
typedef __bf16 bf16x8 __attribute__((ext_vector_type(8)));
typedef float f32x4 __attribute__((ext_vector_type(4)));

// Problem dims
#define NQ   32
#define NN_  128
#define TT   352
#define DD   768
#define NH   8
#define HDIM 96
#define LSEQ 512
#define TSPLIT 160          // NQ + NN
#define FFD  3072
#define NLAYER 6
#define NBATCH 16

// ---------------------------------------------------------------------------
// bt-GEMM (bf16 internal): C[M,N] = act(alpha * A[M,K] @ Bt[N,K]^T + bias[N])
// 128x128 tile, BK=32, 256 threads (4 waves, 2x2 of 64x64), mfma 16x16x32.
// m97-style staging: global_load_lds width=16, LDS dest = wave base + lane*16B.
// Batched via grid.z: z1 = z/zdiv, z2 = z%zdiv.
// ---------------------------------------------------------------------------
template <int ACT>
__global__ __launch_bounds__(256) void gemm_bt(
    const bf16* __restrict__ A, const bf16* __restrict__ Bt,
    bf16* __restrict__ C, const float* __restrict__ bias,
    int K, int lda, int ldb, int ldc, int zdiv,
    long sA1, long sA2, long sB1, long sB2, long sC1, long sC2,
    float alpha, int Nstore)
{
    __shared__ __attribute__((aligned(16))) bf16 As[128 * 32];
    __shared__ __attribute__((aligned(16))) bf16 Bs[128 * 32];

    const int bz = blockIdx.z;
    const int z1 = bz / zdiv, z2 = bz % zdiv;
    A  += (size_t)z1 * sA1 + (size_t)z2 * sA2;
    Bt += (size_t)z1 * sB1 + (size_t)z2 * sB2;
    C  += (size_t)z1 * sC1 + (size_t)z2 * sC2;

    const int n0 = blockIdx.x * 128, m0 = blockIdx.y * 128;
    const int t = threadIdx.x;
    const int w = t >> 6, l = t & 63;
    const int wm = w >> 1, wn = w & 1;
    const int lr = l & 15, quad = l >> 4;

    f32x4 acc[4][4] = {};

    // staging: wave w, call c covers flat tile elems [(w*2+c)*512, +512);
    // flat f -> row f>>5, col f&31 (tile is [128][32] bf16).
    // LDS dest is wave-uniform base; lane lands at base + lane*16B (HW rule).
    const int f0 = w * 1024 + l * 8;
    const int ra0 = f0 >> 5, ca0 = f0 & 31;
    const int ra1 = (f0 + 512) >> 5, ca1 = (f0 + 512) & 31;
    bf16* ldsA0 = &As[w * 1024];
    bf16* ldsA1 = &As[w * 1024 + 512];
    bf16* ldsB0 = &Bs[w * 1024];
    bf16* ldsB1 = &Bs[w * 1024 + 512];
    const bf16* a0 = A  + (size_t)(m0 + ra0) * lda + ca0;
    const bf16* a1 = A  + (size_t)(m0 + ra1) * lda + ca1;
    const bf16* b0 = Bt + (size_t)(n0 + ra0) * ldb + ca0;
    const bf16* b1 = Bt + (size_t)(n0 + ra1) * ldb + ca1;

    for (int k0 = 0; k0 < K; k0 += 32) {
        __syncthreads();                       // prev iter's LDS reads done
        __builtin_amdgcn_global_load_lds(
            (const __attribute__((address_space(1))) void*)(a0 + k0),
            (__attribute__((address_space(3))) void*)ldsA0, 16, 0, 0);
        __builtin_amdgcn_global_load_lds(
            (const __attribute__((address_space(1))) void*)(a1 + k0),
            (__attribute__((address_space(3))) void*)ldsA1, 16, 0, 0);
        __builtin_amdgcn_global_load_lds(
            (const __attribute__((address_space(1))) void*)(b0 + k0),
            (__attribute__((address_space(3))) void*)ldsB0, 16, 0, 0);
        __builtin_amdgcn_global_load_lds(
            (const __attribute__((address_space(1))) void*)(b1 + k0),
            (__attribute__((address_space(3))) void*)ldsB1, 16, 0, 0);
        __syncthreads();                       // staged data visible

        bf16x8 af[4], bf_[4];
#pragma unroll
        for (int i = 0; i < 4; ++i)
            af[i] = *(const bf16x8*)&As[(wm * 64 + i * 16 + lr) * 32 + quad * 8];
#pragma unroll
        for (int j = 0; j < 4; ++j)
            bf_[j] = *(const bf16x8*)&Bs[(wn * 64 + j * 16 + lr) * 32 + quad * 8];
#pragma unroll
        for (int i = 0; i < 4; ++i)
#pragma unroll
            for (int j = 0; j < 4; ++j)
                acc[i][j] = __builtin_amdgcn_mfma_f32_16x16x32_bf16(af[i], bf_[j], acc[i][j], 0, 0, 0);
    }

    // epilogue: C/D layout col = lane&15, row = quad*4 + reg (m89/m91-verified)
#pragma unroll
    for (int i = 0; i < 4; ++i) {
        const int grow = m0 + wm * 64 + i * 16 + quad * 4;
#pragma unroll
        for (int j = 0; j < 4; ++j) {
            const int gcol = n0 + wn * 64 + j * 16 + lr;
            if (gcol >= Nstore) continue;
            float bv = bias ? bias[gcol] : 0.0f;
#pragma unroll
            for (int r = 0; r < 4; ++r) {
                float v = acc[i][j][r] * alpha + bv;
                if (ACT == 1) v = 0.5f * v * (1.0f + erff(v * 0.70710678118654752f));
                C[(size_t)(grow + r) * ldc + gcol] = (bf16)v;
            }
        }
    }
}

// ---------------------------------------------------------------------------
// transpose fp32 weight [R][C] -> bf16 [C][R]
// ---------------------------------------------------------------------------
__global__ void transpose_w(const float* __restrict__ in, bf16* __restrict__ out,
                            int R, int C)
{
    __shared__ bf16 tile[32][33];
    const int c0 = blockIdx.x * 32, r0 = blockIdx.y * 32;
    const int tx = threadIdx.x & 31, ty = threadIdx.x >> 5;
    for (int i = ty; i < 32; i += 8)
        tile[i][tx] = (bf16)in[(size_t)(r0 + i) * C + c0 + tx];
    __syncthreads();
    for (int i = ty; i < 32; i += 8)
        out[(size_t)(c0 + i) * R + r0 + tx] = tile[tx][i];
}

// fp32 -> bf16 elementwise
__global__ void cvt_bf16(const float* __restrict__ in, bf16* __restrict__ out, int n)
{
    const int idx = blockIdx.x * 256 + threadIdx.x;
    if (idx < n) out[idx] = (bf16)in[idx];
}

// vT[z][d][l] = qkv[zb][l][1536 + h*96 + d], z = zb*8+h (zb = chunk-local
// batch). Rows d=96..127 zero-filled (pad for 128-wide staging).
__global__ void transpose_v(const bf16* __restrict__ qkv, bf16* __restrict__ vT)
{
    __shared__ bf16 tile[32][33];
    const int z = blockIdx.z;
    const int zb = z >> 3, h = z & 7;
    const bf16* src = qkv + (size_t)zb * LSEQ * 2304 + 1536 + h * HDIM;
    bf16* dst = vT + (size_t)z * 128 * LSEQ;
    const int l0 = blockIdx.x * 32, d0 = blockIdx.y * 32;
    const int tx = threadIdx.x & 31, ty = threadIdx.x >> 5;
    for (int i = ty; i < 32; i += 8)
        tile[i][tx] = (d0 + tx < HDIM) ? src[(size_t)(l0 + i) * 2304 + d0 + tx]
                                       : (bf16)0.f;
    __syncthreads();
    for (int i = ty; i < 32; i += 8)
        dst[(size_t)(d0 + i) * LSEQ + l0 + tx] = tile[tx][i];
}

// ---------------------------------------------------------------------------
// reductions / LN
// ---------------------------------------------------------------------------
__device__ __forceinline__ void block_reduce_2(float& a, float& b)
{
#pragma unroll
    for (int off = 32; off; off >>= 1) {
        a += __shfl_xor(a, off);
        b += __shfl_xor(b, off);
    }
    __shared__ float sa[4], sb[4];
    const int w = threadIdx.x >> 6;
    if ((threadIdx.x & 63) == 0) { sa[w] = a; sb[w] = b; }
    __syncthreads();
    a = sa[0] + sa[1] + sa[2] + sa[3];
    b = sb[0] + sb[1] + sb[2] + sb[3];
}

// x[row] = LN(concat_src(row) + pos[l] + tok); fp32 inputs, bf16 out
__global__ void embed_ln(const float* __restrict__ qtok, const bf16* __restrict__ gfeat,
                         const float* __restrict__ text, const float* __restrict__ pos,
                         const float* __restrict__ tok, const float* __restrict__ g,
                         const float* __restrict__ bb, bf16* __restrict__ x)
{
    const int row = blockIdx.x;           // b*512 + l
    const int l = row & 511, b = row >> 9;
    const int t = threadIdx.x;

    float vals[3], s = 0.f, sq = 0.f;
#pragma unroll
    for (int c = 0; c < 3; ++c) {
        const int d = t + c * 256;
        float base;
        if (l < NQ)           base = qtok[(size_t)l * DD + d];
        else if (l < TSPLIT)  base = (float)gfeat[((size_t)b * NN_ + (l - NQ)) * DD + d];
        else                  base = text[((size_t)b * TT + (l - TSPLIT)) * DD + d];
        float v = base + pos[(size_t)l * DD + d] + tok[d];
        vals[c] = v; s += v; sq += v * v;
    }
    block_reduce_2(s, sq);
    const float mean = s * (1.f / 768.f);
    const float var = sq * (1.f / 768.f) - mean * mean;
    const float rs = rsqrtf(var + 1e-12f);
    bf16* o = x + (size_t)row * DD;
#pragma unroll
    for (int c = 0; c < 3; ++c) {
        const int d = t + c * 256;
        o[d] = (bf16)((vals[c] - mean) * rs * g[d] + bb[d]);
    }
}

// out[row] = LN(X[row] + Y[row]); safe for out==X; fp32 gains
__global__ void ln_rows(const bf16* __restrict__ X, const bf16* __restrict__ Y,
                        bf16* __restrict__ Out, const float* __restrict__ g,
                        const float* __restrict__ bb)
{
    const int row = blockIdx.x;
    const int t = threadIdx.x;
    const bf16* xr = X + (size_t)row * DD;
    const bf16* yr = Y + (size_t)row * DD;
    float vals[3], s = 0.f, sq = 0.f;
#pragma unroll
    for (int c = 0; c < 3; ++c) {
        const int d = t + c * 256;
        float v = (float)xr[d] + (float)yr[d];
        vals[c] = v; s += v; sq += v * v;
    }
    block_reduce_2(s, sq);
    const float mean = s * (1.f / 768.f);
    const float var = sq * (1.f / 768.f) - mean * mean;
    const float rs = rsqrtf(var + 1e-12f);
    bf16* o = Out + (size_t)row * DD;
#pragma unroll
    for (int c = 0; c < 3; ++c) {
        const int d = t + c * 256;
        o[d] = (bf16)((vals[c] - mean) * rs * g[d] + bb[d]);
    }
}

// ---------------------------------------------------------------------------
// softmax with ITG prefix-LM mask bias, in place on S (bf16), 1 wave per row
// S layout: [z = zb*8+h][512 rows][512 cols]; global batch = b0 + zb
// ---------------------------------------------------------------------------
__global__ void softmax_mask(bf16* __restrict__ S, const int* __restrict__ tatts,
                             const int* __restrict__ gmask, int b0)
{
    const int wid = blockIdx.x * 4 + (threadIdx.x >> 6);
    const int lane = threadIdx.x & 63;
    const int i = wid & 511;
    const int bh = wid >> 9;
    const int b = b0 + (bh >> 3);
    bf16* p = S + (size_t)wid * 512;

    const int keep_i = (i < NQ) ? 1 : (i < TSPLIT ? gmask[b * NN_ + i - NQ]
                                                  : tatts[b * TT + i - TSPLIT]);
    float v[8];
    float m = -INFINITY;
#pragma unroll
    for (int c = 0; c < 8; ++c) {
        const int j = c * 64 + lane;
        const int keep_j = (j < NQ) ? 1 : (j < TSPLIT ? gmask[b * NN_ + j - NQ]
                                                      : tatts[b * TT + j - TSPLIT]);
        bool ok = keep_i && keep_j;
        if (i < TSPLIT && j >= TSPLIT) ok = false;             // prefix can't see text
        if (i >= TSPLIT && j >= TSPLIT && i < j) ok = false;   // causal in text block
        float s = (float)p[j] + (ok ? 0.f : -1e9f);
        v[c] = s;
        m = fmaxf(m, s);
    }
#pragma unroll
    for (int off = 32; off; off >>= 1) m = fmaxf(m, __shfl_xor(m, off));
    float sum = 0.f;
#pragma unroll
    for (int c = 0; c < 8; ++c) { v[c] = __expf(v[c] - m); sum += v[c]; }
#pragma unroll
    for (int off = 32; off; off >>= 1) sum += __shfl_xor(sum, off);
    const float inv = 1.f / sum;
#pragma unroll
    for (int c = 0; c < 8; ++c) p[c * 64 + lane] = (bf16)(v[c] * inv);
}

// d_out[b][t][d] = x[b][TSPLIT+t][d]  (fp32 out)
__global__ void copy_out(const bf16* __restrict__ x, float* __restrict__ out)
{
    const size_t idx = (size_t)blockIdx.x * 256 + threadIdx.x;   // < 16*352*768
    const int d = idx % DD;
    const size_t row = idx / DD;
    const int t = row % TT;
    const int b = row / TT;
    out[idx] = (float)x[((size_t)b * LSEQ + TSPLIT + t) * DD + d];
}

// ---------------------------------------------------------------------------
// host side
// ---------------------------------------------------------------------------
static void launch_gemm(const bf16* A, const bf16* Bt, bf16* C, const float* bias,
                        int M, int K, int lda, int ldb, int ldc,
                        int batches, int zdiv,
                        long sA1, long sA2, long sB1, long sB2, long sC1, long sC2,
                        float alpha, int Nstore, int act, hipStream_t stream)
{
    dim3 grid((Nstore + 127) / 128, M / 128, batches);
    if (act)
        gemm_bt<1><<<grid, 256, 0, stream>>>(A, Bt, C, bias, K, lda, ldb, ldc, zdiv,
                                             sA1, sA2, sB1, sB2, sC1, sC2, alpha, Nstore);
    else
        gemm_bt<0><<<grid, 256, 0, stream>>>(A, Bt, C, bias, K, lda, ldb, ldc, zdiv,
                                             sA1, sA2, sB1, sB2, sC1, sC2, alpha, Nstore);
}

extern "C" void kernel_launch(void* const* d_in, const int* in_sizes, int n_in,
                              void* d_out, int out_size, void* d_ws, size_t ws_size,
                              hipStream_t stream)
{
    // Reference dtypes: all float32 except text_atts / graph_mask (int32).
    const float* gnf     = (const float*)d_in[0];
    const float* text    = (const float*)d_in[1];
    const int*   tatts   = (const int*)d_in[2];
    const int*   gmask   = (const int*)d_in[3];
    const float* qtok    = (const float*)d_in[4];
    const float* gproj_w = (const float*)d_in[5];
    const float* gproj_b = (const float*)d_in[6];
    const float* pos     = (const float*)d_in[7];
    const float* tok     = (const float*)d_in[8];
    const float* eg      = (const float*)d_in[9];
    const float* eb      = (const float*)d_in[10];
    const float* qkv_w   = (const float*)d_in[11];
    const float* qkv_b   = (const float*)d_in[12];
    const float* ao_w    = (const float*)d_in[13];
    const float* ao_b    = (const float*)d_in[14];
    const float* ln1g    = (const float*)d_in[15];
    const float* ln1b    = (const float*)d_in[16];
    const float* ff1_w   = (const float*)d_in[17];
    const float* ff1_b   = (const float*)d_in[18];
    const float* ff2_w   = (const float*)d_in[19];
    const float* ff2_b   = (const float*)d_in[20];
    const float* ln2g    = (const float*)d_in[21];
    const float* ln2b    = (const float*)d_in[22];
    float* out = (float*)d_out;

    // Adaptive layout: big path (unchunked, 168.9 MB) if ws permits,
    // else the round-3-verified 81.8 MB chunked layout. ws_size is constant
    // across calls, so the work is identical every launch.
    const bool big = ws_size >= (size_t)169000000;
    const int CB = big ? 16 : 4;     // batches per attention chunk
    const int NC = NBATCH / CB;      // attention chunks
    const int FC = big ? 1 : 2;      // ffn chunks
    const int FM = 8192 / FC;        // rows per ffn chunk

    bf16* ws = (bf16*)d_ws;
    size_t off = 0;
    auto alloc = [&](size_t n) { bf16* p = ws + off; off += n; return p; };
    bf16* wt1  = alloc(2359296);                       // current B^T (qkv/ao/ff1)
    bf16* wt2  = alloc(2359296);                       // ff2^T
    bf16* x    = alloc(6291456);                       // residual stream
    bf16* qkvb = alloc((size_t)CB * 512 * 2304);       // qkv for one chunk
    bf16* ctx  = alloc(6291456);                       // attention context (full)
    bf16* t1   = alloc(6291456);                       // sublayer out / gfeat
    bf16* u    = alloc(big ? 41943040 : 12582912);     // union region
    bf16* vTc  = u;                                    // CB*8 * 128*512
    bf16* Sc   = u + (size_t)CB * 524288;              // CB*8 * 512*512
    bf16* hbuf = u;                                    // FM * 3072 (ffn phase)
    bf16* gfeat = t1;                                  // pre-loop only
    bf16* gnfb  = qkvb;                                // pre-loop only

    dim3 blk(256);

    // graph projection: gfeat[2048,768] = bf16(gnf) @ bf16(gproj_w) + b
    cvt_bf16<<<6144, blk, 0, stream>>>(gnf, gnfb, 1572864);
    transpose_w<<<dim3(24, 24), blk, 0, stream>>>(gproj_w, wt1, 768, 768);
    launch_gemm(gnfb, wt1, gfeat, gproj_b, 2048, 768, 768, 768, 768,
                1, 1, 0, 0, 0, 0, 0, 0, 1.f, 768, 0, stream);
    embed_ln<<<8192, blk, 0, stream>>>(qtok, gfeat, text, pos, tok, eg, eb, x);

    const float scale = 0.10206207261596577f;  // 1/sqrt(96)
    for (int i = 0; i < NLAYER; ++i) {
        transpose_w<<<dim3(72, 24), blk, 0, stream>>>(
            qkv_w + (size_t)i * 768 * 2304, wt1, 768, 2304);
        for (int c = 0; c < NC; ++c) {
            launch_gemm(x + (size_t)c * CB * 512 * 768, wt1, qkvb, qkv_b + i * 2304,
                        CB * 512, 768, 768, 768, 2304, 1, 1, 0, 0, 0, 0, 0, 0,
                        1.f, 2304, 0, stream);
            transpose_v<<<dim3(16, 4, CB * 8), blk, 0, stream>>>(qkvb, vTc);
            launch_gemm(qkvb, qkvb + 768, Sc, nullptr, 512, 96, 2304, 2304, 512,
                        CB * 8, 8, 1179648, 96, 1179648, 96, 2097152, 262144,
                        scale, 512, 0, stream);
            softmax_mask<<<CB * 1024, blk, 0, stream>>>(Sc, tatts, gmask, c * CB);
            launch_gemm(Sc, vTc, ctx + (size_t)c * CB * 512 * 768, nullptr,
                        512, 512, 512, 512, 768,
                        CB * 8, 8, 2097152, 262144, 524288, 65536, 393216, 96,
                        1.f, 96, 0, stream);
        }
        transpose_w<<<dim3(24, 24), blk, 0, stream>>>(
            ao_w + (size_t)i * 589824, wt1, 768, 768);
        launch_gemm(ctx, wt1, t1, ao_b + i * 768, 8192, 768, 768, 768, 768,
                    1, 1, 0, 0, 0, 0, 0, 0, 1.f, 768, 0, stream);
        ln_rows<<<8192, blk, 0, stream>>>(x, t1, x, ln1g + i * 768, ln1b + i * 768);

        transpose_w<<<dim3(96, 24), blk, 0, stream>>>(
            ff1_w + (size_t)i * 2359296, wt1, 768, 3072);
        transpose_w<<<dim3(24, 96), blk, 0, stream>>>(
            ff2_w + (size_t)i * 2359296, wt2, 3072, 768);
        for (int c = 0; c < FC; ++c) {
            launch_gemm(x + (size_t)c * FM * 768, wt1, hbuf, ff1_b + i * 3072,
                        FM, 768, 768, 768, 3072, 1, 1, 0, 0, 0, 0, 0, 0,
                        1.f, 3072, 1, stream);
            launch_gemm(hbuf, wt2, t1 + (size_t)c * FM * 768, ff2_b + i * 768,
                        FM, 3072, 3072, 3072, 768, 1, 1, 0, 0, 0, 0, 0, 0,
                        1.f, 768, 0, stream);
        }
        ln_rows<<<8192, blk, 0, stream>>>(x, t1, x, ln2g + i * 768, ln2b + i * 768);
    }

    copy_out<<<16896, blk, 0, stream>>>(x, out);

    (void)in_sizes; (void)n_in; (void)out_size;
}

// Round 5
// 2293.234 us; speedup vs baseline: 1.5852x; 1.0669x over previous
//
#include <hip/hip_runtime.h>
#include <math.h>

typedef __bf16 bf16;
typedef __bf16 bf16x8 __attribute__((ext_vector_type(8)));
typedef float f32x4 __attribute__((ext_vector_type(4)));

// Problem dims
#define NQ   32
#define NN_  128
#define TT   352
#define DD   768
#define NH   8
#define HDIM 96
#define LSEQ 512
#define TSPLIT 160          // NQ + NN
#define FFD  3072
#define NLAYER 6
#define NBATCH 16

// ---------------------------------------------------------------------------
// bt-GEMM (bf16 internal): C[M,N] = act(alpha * A[M,K] @ Bt[N,K]^T + bias[N])
// 128x128 tile, BK=32, 256 threads (4 waves, 2x2 of 64x64), mfma 16x16x32.
// m97-style staging: global_load_lds width=16, LDS dest = wave base + lane*16B.
// ---------------------------------------------------------------------------
template <int ACT>
__global__ __launch_bounds__(256) void gemm_bt(
    const bf16* __restrict__ A, const bf16* __restrict__ Bt,
    bf16* __restrict__ C, const float* __restrict__ bias,
    int K, int lda, int ldb, int ldc, float alpha, int Nstore)
{
    __shared__ __attribute__((aligned(16))) bf16 As[128 * 32];
    __shared__ __attribute__((aligned(16))) bf16 Bs[128 * 32];

    const int n0 = blockIdx.x * 128, m0 = blockIdx.y * 128;
    const int t = threadIdx.x;
    const int w = t >> 6, l = t & 63;
    const int wm = w >> 1, wn = w & 1;
    const int lr = l & 15, quad = l >> 4;

    f32x4 acc[4][4] = {};

    const int f0 = w * 1024 + l * 8;
    const int ra0 = f0 >> 5, ca0 = f0 & 31;
    const int ra1 = (f0 + 512) >> 5, ca1 = (f0 + 512) & 31;
    bf16* ldsA0 = &As[w * 1024];
    bf16* ldsA1 = &As[w * 1024 + 512];
    bf16* ldsB0 = &Bs[w * 1024];
    bf16* ldsB1 = &Bs[w * 1024 + 512];
    const bf16* a0 = A  + (size_t)(m0 + ra0) * lda + ca0;
    const bf16* a1 = A  + (size_t)(m0 + ra1) * lda + ca1;
    const bf16* b0 = Bt + (size_t)(n0 + ra0) * ldb + ca0;
    const bf16* b1 = Bt + (size_t)(n0 + ra1) * ldb + ca1;

    for (int k0 = 0; k0 < K; k0 += 32) {
        __syncthreads();
        __builtin_amdgcn_global_load_lds(
            (const __attribute__((address_space(1))) void*)(a0 + k0),
            (__attribute__((address_space(3))) void*)ldsA0, 16, 0, 0);
        __builtin_amdgcn_global_load_lds(
            (const __attribute__((address_space(1))) void*)(a1 + k0),
            (__attribute__((address_space(3))) void*)ldsA1, 16, 0, 0);
        __builtin_amdgcn_global_load_lds(
            (const __attribute__((address_space(1))) void*)(b0 + k0),
            (__attribute__((address_space(3))) void*)ldsB0, 16, 0, 0);
        __builtin_amdgcn_global_load_lds(
            (const __attribute__((address_space(1))) void*)(b1 + k0),
            (__attribute__((address_space(3))) void*)ldsB1, 16, 0, 0);
        __syncthreads();

        bf16x8 af[4], bf_[4];
#pragma unroll
        for (int i = 0; i < 4; ++i)
            af[i] = *(const bf16x8*)&As[(wm * 64 + i * 16 + lr) * 32 + quad * 8];
#pragma unroll
        for (int j = 0; j < 4; ++j)
            bf_[j] = *(const bf16x8*)&Bs[(wn * 64 + j * 16 + lr) * 32 + quad * 8];
#pragma unroll
        for (int i = 0; i < 4; ++i)
#pragma unroll
            for (int j = 0; j < 4; ++j)
                acc[i][j] = __builtin_amdgcn_mfma_f32_16x16x32_bf16(af[i], bf_[j], acc[i][j], 0, 0, 0);
    }

#pragma unroll
    for (int i = 0; i < 4; ++i) {
        const int grow = m0 + wm * 64 + i * 16 + quad * 4;
#pragma unroll
        for (int j = 0; j < 4; ++j) {
            const int gcol = n0 + wn * 64 + j * 16 + lr;
            if (gcol >= Nstore) continue;
            float bv = bias ? bias[gcol] : 0.0f;
#pragma unroll
            for (int r = 0; r < 4; ++r) {
                float v = acc[i][j][r] * alpha + bv;
                if (ACT == 1) v = 0.5f * v * (1.0f + erff(v * 0.70710678118654752f));
                C[(size_t)(grow + r) * ldc + gcol] = (bf16)v;
            }
        }
    }
}

// ---------------------------------------------------------------------------
// Flash attention with ITG prefix-LM mask.
// Block = 256 thr (4 waves). Block handles 64 Q-rows of one (b,h).
// Wave w owns Q-rows [w*16, w*16+16). K/V tiles of 64 cols, online softmax.
// Structural tile skip: tile (q0,j0) fully masked iff j0>=TSPLIT && j0>q0+63
// (prefix rows can't see text; causal within text) — skipped tiles contribute
// exp(~-1e9)=0 exactly in fp32, matching the reference's additive -1e9 mask.
// qkv: [B*512][2304] rows b*512+l; Q at h*96, K +768, V +1536.
// ctx: [B*512][768].
// ---------------------------------------------------------------------------
__global__ __launch_bounds__(256) void flash_attn(
    const bf16* __restrict__ qkv, bf16* __restrict__ ctx,
    const int* __restrict__ tatts, const int* __restrict__ gmask)
{
    // pads chosen for conflict-free b128 reads: 104 = 96+8 (stride 208 B),
    // 72 = 64+8 (stride 144 B == 4 banks mod 32 -> 2-way, free).
    __shared__ __attribute__((aligned(16))) bf16 Qs[64 * 104];
    __shared__ __attribute__((aligned(16))) bf16 Ks[64 * 104];
    __shared__ __attribute__((aligned(16))) bf16 Vs[96 * 72];   // V^T tile
    __shared__ __attribute__((aligned(16))) bf16 Ps[64 * 72];
    __shared__ int keep[512];

    const int qt = blockIdx.x;       // 0..7
    const int bh = blockIdx.y;       // 0..127
    const int b = bh >> 3, h = bh & 7;
    const int q0 = qt * 64;
    const int t = threadIdx.x;
    const int w = t >> 6, l = t & 63;
    const int lr = l & 15, quad = l >> 4;
    const float scale = 0.10206207261596577f;  // 1/sqrt(96)

    const bf16* qbase = qkv + (size_t)b * 512 * 2304 + h * 96;
    const bf16* kbase = qbase + 768;
    const bf16* vbase = qbase + 1536;

    // keep vector for this batch
    for (int j = t; j < 512; j += 256)
        keep[j] = (j < NQ) ? 1 : (j < TSPLIT ? gmask[b * NN_ + j - NQ]
                                             : tatts[b * TT + j - TSPLIT]);

    // stage Q tile (64 x 96), rows q0..q0+63
#pragma unroll
    for (int c = 0; c < 3; ++c) {
        const int idx = t * 8 + c * 2048;
        const int r = idx / 96, d = idx % 96;
        *(bf16x8*)&Qs[r * 104 + d] =
            *(const bf16x8*)&qbase[(size_t)(q0 + r) * 2304 + d];
    }
    __syncthreads();

    // this lane's 4 row indices / keeps (rows w*16 + quad*4 + r)
    int ki[4];
    int ig[4];
#pragma unroll
    for (int r = 0; r < 4; ++r) {
        ig[r] = q0 + w * 16 + quad * 4 + r;
        ki[r] = keep[ig[r]];
    }

    float m_run[4] = {-1e30f, -1e30f, -1e30f, -1e30f};
    float l_run[4] = {0.f, 0.f, 0.f, 0.f};
    f32x4 oc[6] = {};

    const int JMAX = (qt < 3) ? 128 : q0;
    for (int j0 = 0; j0 <= JMAX; j0 += 64) {
        __syncthreads();    // prior tile's PV reads of Ks/Vs/Ps complete
        // stage K tile and transposed V tile
#pragma unroll
        for (int c = 0; c < 3; ++c) {
            const int idx = t * 8 + c * 2048;
            const int r = idx / 96, d = idx % 96;
            *(bf16x8*)&Ks[r * 104 + d] =
                *(const bf16x8*)&kbase[(size_t)(j0 + r) * 2304 + d];
            bf16x8 vv = *(const bf16x8*)&vbase[(size_t)(j0 + r) * 2304 + d];
#pragma unroll
            for (int jj = 0; jj < 8; ++jj)
                Vs[(d + jj) * 72 + r] = vv[jj];
        }
        __syncthreads();

        // S tile: this wave's 16 rows x 64 cols
        bf16x8 aq[3];
#pragma unroll
        for (int ds = 0; ds < 3; ++ds)
            aq[ds] = *(const bf16x8*)&Qs[(w * 16 + lr) * 104 + ds * 32 + quad * 8];
        f32x4 sc[4];
#pragma unroll
        for (int cb = 0; cb < 4; ++cb) {
            f32x4 a = {};
#pragma unroll
            for (int ds = 0; ds < 3; ++ds) {
                bf16x8 bk = *(const bf16x8*)&Ks[(cb * 16 + lr) * 104 + ds * 32 + quad * 8];
                a = __builtin_amdgcn_mfma_f32_16x16x32_bf16(aq[ds], bk, a, 0, 0, 0);
            }
            sc[cb] = a;
        }

        // scale + mask bias; tile row max
        float tm[4] = {-1e30f, -1e30f, -1e30f, -1e30f};
#pragma unroll
        for (int cb = 0; cb < 4; ++cb) {
            const int jg = j0 + cb * 16 + lr;
            const int kj = keep[jg];
#pragma unroll
            for (int r = 0; r < 4; ++r) {
                const int i = ig[r];
                bool ok = ki[r] && kj;
                if (i < TSPLIT && jg >= TSPLIT) ok = false;           // prefix !see text
                if (i >= TSPLIT && jg >= TSPLIT && i < jg) ok = false; // causal
                float s = sc[cb][r] * scale + (ok ? 0.f : -1e9f);
                sc[cb][r] = s;
                tm[r] = fmaxf(tm[r], s);
            }
        }
#pragma unroll
        for (int off = 1; off < 16; off <<= 1)
#pragma unroll
            for (int r = 0; r < 4; ++r)
                tm[r] = fmaxf(tm[r], __shfl_xor(tm[r], off));

        // online-softmax update
        float alpha_[4], ts[4] = {0.f, 0.f, 0.f, 0.f};
#pragma unroll
        for (int r = 0; r < 4; ++r) {
            const float mn = fmaxf(m_run[r], tm[r]);
            alpha_[r] = __expf(m_run[r] - mn);
            m_run[r] = mn;
            l_run[r] *= alpha_[r];
        }
#pragma unroll
        for (int db = 0; db < 6; ++db)
#pragma unroll
            for (int r = 0; r < 4; ++r)
                oc[db][r] *= alpha_[r];

        // P = exp(S - m), write to LDS (C-layout -> A-layout roundtrip)
#pragma unroll
        for (int cb = 0; cb < 4; ++cb)
#pragma unroll
            for (int r = 0; r < 4; ++r) {
                const float p = __expf(sc[cb][r] - m_run[r]);
                ts[r] += p;
                Ps[(w * 16 + quad * 4 + r) * 72 + cb * 16 + lr] = (bf16)p;
            }
#pragma unroll
        for (int off = 1; off < 16; off <<= 1)
#pragma unroll
            for (int r = 0; r < 4; ++r)
                ts[r] += __shfl_xor(ts[r], off);
#pragma unroll
        for (int r = 0; r < 4; ++r) l_run[r] += ts[r];

        __syncthreads();    // Ps/Vs visible to all lanes

        // O += P @ V
#pragma unroll
        for (int l0 = 0; l0 < 64; l0 += 32) {
            bf16x8 ap = *(const bf16x8*)&Ps[(w * 16 + lr) * 72 + l0 + quad * 8];
#pragma unroll
            for (int db = 0; db < 6; ++db) {
                bf16x8 bv = *(const bf16x8*)&Vs[(db * 16 + lr) * 72 + l0 + quad * 8];
                oc[db] = __builtin_amdgcn_mfma_f32_16x16x32_bf16(ap, bv, oc[db], 0, 0, 0);
            }
        }
    }

    // epilogue: ctx[b][row][h*96 + d] = O / l
#pragma unroll
    for (int r = 0; r < 4; ++r) {
        const float inv = 1.f / l_run[r];
        bf16* orow = ctx + ((size_t)b * 512 + ig[r]) * 768 + h * 96;
#pragma unroll
        for (int db = 0; db < 6; ++db)
            orow[db * 16 + lr] = (bf16)(oc[db][r] * inv);
    }
}

// ---------------------------------------------------------------------------
// transpose fp32 weight [R][C] -> bf16 [C][R]
// ---------------------------------------------------------------------------
__global__ void transpose_w(const float* __restrict__ in, bf16* __restrict__ out,
                            int R, int C)
{
    __shared__ bf16 tile[32][33];
    const int c0 = blockIdx.x * 32, r0 = blockIdx.y * 32;
    const int tx = threadIdx.x & 31, ty = threadIdx.x >> 5;
    for (int i = ty; i < 32; i += 8)
        tile[i][tx] = (bf16)in[(size_t)(r0 + i) * C + c0 + tx];
    __syncthreads();
    for (int i = ty; i < 32; i += 8)
        out[(size_t)(c0 + i) * R + r0 + tx] = tile[tx][i];
}

// fp32 -> bf16 elementwise
__global__ void cvt_bf16(const float* __restrict__ in, bf16* __restrict__ out, int n)
{
    const int idx = blockIdx.x * 256 + threadIdx.x;
    if (idx < n) out[idx] = (bf16)in[idx];
}

// ---------------------------------------------------------------------------
// reductions / LN
// ---------------------------------------------------------------------------
__device__ __forceinline__ void block_reduce_2(float& a, float& b)
{
#pragma unroll
    for (int off = 32; off; off >>= 1) {
        a += __shfl_xor(a, off);
        b += __shfl_xor(b, off);
    }
    __shared__ float sa[4], sb[4];
    const int w = threadIdx.x >> 6;
    if ((threadIdx.x & 63) == 0) { sa[w] = a; sb[w] = b; }
    __syncthreads();
    a = sa[0] + sa[1] + sa[2] + sa[3];
    b = sb[0] + sb[1] + sb[2] + sb[3];
}

// x[row] = LN(concat_src(row) + pos[l] + tok); fp32 inputs, bf16 out
__global__ void embed_ln(const float* __restrict__ qtok, const bf16* __restrict__ gfeat,
                         const float* __restrict__ text, const float* __restrict__ pos,
                         const float* __restrict__ tok, const float* __restrict__ g,
                         const float* __restrict__ bb, bf16* __restrict__ x)
{
    const int row = blockIdx.x;           // b*512 + l
    const int l = row & 511, b = row >> 9;
    const int t = threadIdx.x;

    float vals[3], s = 0.f, sq = 0.f;
#pragma unroll
    for (int c = 0; c < 3; ++c) {
        const int d = t + c * 256;
        float base;
        if (l < NQ)           base = qtok[(size_t)l * DD + d];
        else if (l < TSPLIT)  base = (float)gfeat[((size_t)b * NN_ + (l - NQ)) * DD + d];
        else                  base = text[((size_t)b * TT + (l - TSPLIT)) * DD + d];
        float v = base + pos[(size_t)l * DD + d] + tok[d];
        vals[c] = v; s += v; sq += v * v;
    }
    block_reduce_2(s, sq);
    const float mean = s * (1.f / 768.f);
    const float var = sq * (1.f / 768.f) - mean * mean;
    const float rs = rsqrtf(var + 1e-12f);
    bf16* o = x + (size_t)row * DD;
#pragma unroll
    for (int c = 0; c < 3; ++c) {
        const int d = t + c * 256;
        o[d] = (bf16)((vals[c] - mean) * rs * g[d] + bb[d]);
    }
}

// out[row] = LN(X[row] + Y[row]); safe for out==X; fp32 gains
__global__ void ln_rows(const bf16* __restrict__ X, const bf16* __restrict__ Y,
                        bf16* __restrict__ Out, const float* __restrict__ g,
                        const float* __restrict__ bb)
{
    const int row = blockIdx.x;
    const int t = threadIdx.x;
    const bf16* xr = X + (size_t)row * DD;
    const bf16* yr = Y + (size_t)row * DD;
    float vals[3], s = 0.f, sq = 0.f;
#pragma unroll
    for (int c = 0; c < 3; ++c) {
        const int d = t + c * 256;
        float v = (float)xr[d] + (float)yr[d];
        vals[c] = v; s += v; sq += v * v;
    }
    block_reduce_2(s, sq);
    const float mean = s * (1.f / 768.f);
    const float var = sq * (1.f / 768.f) - mean * mean;
    const float rs = rsqrtf(var + 1e-12f);
    bf16* o = Out + (size_t)row * DD;
#pragma unroll
    for (int c = 0; c < 3; ++c) {
        const int d = t + c * 256;
        o[d] = (bf16)((vals[c] - mean) * rs * g[d] + bb[d]);
    }
}

// d_out[b][t][d] = x[b][TSPLIT+t][d]  (fp32 out)
__global__ void copy_out(const bf16* __restrict__ x, float* __restrict__ out)
{
    const size_t idx = (size_t)blockIdx.x * 256 + threadIdx.x;   // < 16*352*768
    const int d = idx % DD;
    const size_t row = idx / DD;
    const int t = row % TT;
    const int b = row / TT;
    out[idx] = (float)x[((size_t)b * LSEQ + TSPLIT + t) * DD + d];
}

// ---------------------------------------------------------------------------
// host side
// ---------------------------------------------------------------------------
static void launch_gemm(const bf16* A, const bf16* Bt, bf16* C, const float* bias,
                        int M, int K, int lda, int ldb, int ldc,
                        float alpha, int Nstore, int act, hipStream_t stream)
{
    dim3 grid((Nstore + 127) / 128, M / 128, 1);
    if (act)
        gemm_bt<1><<<grid, 256, 0, stream>>>(A, Bt, C, bias, K, lda, ldb, ldc, alpha, Nstore);
    else
        gemm_bt<0><<<grid, 256, 0, stream>>>(A, Bt, C, bias, K, lda, ldb, ldc, alpha, Nstore);
}

extern "C" void kernel_launch(void* const* d_in, const int* in_sizes, int n_in,
                              void* d_out, int out_size, void* d_ws, size_t ws_size,
                              hipStream_t stream)
{
    // Reference dtypes: all float32 except text_atts / graph_mask (int32).
    const float* gnf     = (const float*)d_in[0];
    const float* text    = (const float*)d_in[1];
    const int*   tatts   = (const int*)d_in[2];
    const int*   gmask   = (const int*)d_in[3];
    const float* qtok    = (const float*)d_in[4];
    const float* gproj_w = (const float*)d_in[5];
    const float* gproj_b = (const float*)d_in[6];
    const float* pos     = (const float*)d_in[7];
    const float* tok     = (const float*)d_in[8];
    const float* eg      = (const float*)d_in[9];
    const float* eb      = (const float*)d_in[10];
    const float* qkv_w   = (const float*)d_in[11];
    const float* qkv_b   = (const float*)d_in[12];
    const float* ao_w    = (const float*)d_in[13];
    const float* ao_b    = (const float*)d_in[14];
    const float* ln1g    = (const float*)d_in[15];
    const float* ln1b    = (const float*)d_in[16];
    const float* ff1_w   = (const float*)d_in[17];
    const float* ff1_b   = (const float*)d_in[18];
    const float* ff2_w   = (const float*)d_in[19];
    const float* ff2_b   = (const float*)d_in[20];
    const float* ln2g    = (const float*)d_in[21];
    const float* ln2b    = (const float*)d_in[22];
    float* out = (float*)d_out;

    // ws layout (bf16 elems), 48,758,784 elems = 97.5 MB (ws >= 169 MB verified
    // in round 4 — big path ran). u-region: qkvb (attn) / hbuf (ffn), disjoint.
    bf16* ws   = (bf16*)d_ws;
    bf16* wt1  = ws;                    // 2,359,296
    bf16* wt2  = wt1 + 2359296;         // 2,359,296
    bf16* x    = wt2 + 2359296;         // 6,291,456
    bf16* ctx  = x   + 6291456;         // 6,291,456
    bf16* t1   = ctx + 6291456;         // 6,291,456
    bf16* u    = t1  + 6291456;         // 25,165,824
    bf16* qkvb = u;                     //   18,874,368 (attn phase)
    bf16* hbuf = u;                     //   25,165,824 (ffn phase)
    bf16* gfeat = t1;                   //    1,572,864 (pre-loop)
    bf16* gnfb  = u;                    //    1,572,864 (pre-loop)

    dim3 blk(256);

    // graph projection: gfeat[2048,768] = bf16(gnf) @ bf16(gproj_w) + b
    cvt_bf16<<<6144, blk, 0, stream>>>(gnf, gnfb, 1572864);
    transpose_w<<<dim3(24, 24), blk, 0, stream>>>(gproj_w, wt1, 768, 768);
    launch_gemm(gnfb, wt1, gfeat, gproj_b, 2048, 768, 768, 768, 768,
                1.f, 768, 0, stream);
    embed_ln<<<8192, blk, 0, stream>>>(qtok, gfeat, text, pos, tok, eg, eb, x);

    for (int i = 0; i < NLAYER; ++i) {
        // qkv = x @ qkv_w[i] + b   [8192, 2304]
        transpose_w<<<dim3(72, 24), blk, 0, stream>>>(
            qkv_w + (size_t)i * 768 * 2304, wt1, 768, 2304);
        launch_gemm(x, wt1, qkvb, qkv_b + i * 2304,
                    8192, 768, 768, 768, 2304, 1.f, 2304, 0, stream);
        // fused attention -> ctx [8192, 768]
        flash_attn<<<dim3(8, 128), blk, 0, stream>>>(qkvb, ctx, tatts, gmask);
        // t1 = ctx @ ao_w[i] + b
        transpose_w<<<dim3(24, 24), blk, 0, stream>>>(
            ao_w + (size_t)i * 589824, wt1, 768, 768);
        launch_gemm(ctx, wt1, t1, ao_b + i * 768,
                    8192, 768, 768, 768, 768, 1.f, 768, 0, stream);
        ln_rows<<<8192, blk, 0, stream>>>(x, t1, x, ln1g + i * 768, ln1b + i * 768);

        // ffn
        transpose_w<<<dim3(96, 24), blk, 0, stream>>>(
            ff1_w + (size_t)i * 2359296, wt1, 768, 3072);
        transpose_w<<<dim3(24, 96), blk, 0, stream>>>(
            ff2_w + (size_t)i * 2359296, wt2, 3072, 768);
        launch_gemm(x, wt1, hbuf, ff1_b + i * 3072,
                    8192, 768, 768, 768, 3072, 1.f, 3072, 1, stream);
        launch_gemm(hbuf, wt2, t1, ff2_b + i * 768,
                    8192, 3072, 3072, 3072, 768, 1.f, 768, 0, stream);
        ln_rows<<<8192, blk, 0, stream>>>(x, t1, x, ln2g + i * 768, ln2b + i * 768);
    }

    copy_out<<<16896, blk, 0, stream>>>(x, out);

    (void)in_sizes; (void)n_in; (void)out_size; (void)ws_size;
}